// Round 8
// baseline (162.140 us; speedup 1.0000x reference)
//
#include <hip/hip_runtime.h>
#include <math.h>
#include <stdint.h>

#define NB 16384
#define NG 10000
#define NGT 313           // ceil(NG/32) g-tiles of 32; tail rows NaN -> scrubbed in peeled iter
#define NCH 20            // g-chunks; chunk c covers tiles [NGT*c/NCH, NGT*(c+1)/NCH)
#define MAXTPC 16         // max tiles/chunk: 16 * 32 rows * 40 B = 20480 B LDS -> 8 blocks/CU

typedef _Float16 half4 __attribute__((ext_vector_type(4)));
typedef _Float16 half8 __attribute__((ext_vector_type(8)));
typedef float    floatx16 __attribute__((ext_vector_type(16)));

// C/D row map for 32x32x16: row = (r&3) + 8*(r>>2) + 4*kh
#define ROWMAP(r, kh) (((r) & 3) + 8 * ((r) >> 2) + 4 * (kh))

__device__ inline float max3f(float a, float b, float c) {
    float d;
    asm("v_max3_f32 %0, %1, %2, %3" : "=v"(d) : "v"(a), "v"(b), "v"(c));
    return d;
}

// p = bitcast( (bits(c) & 0xFFFFFFF0) | F )  -- pack 4-bit field into low mantissa
#define PACKF(p_, c_, F_) \
    asm("v_and_or_b32 %0, %1, %2, " F_ : "=v"(p_) : "v"(c_), "s"(mskc))

// ---- cross-block data through the coherent point (LLC), r2-proven helpers ----
__device__ inline void  pst_f(float* p, size_t i, float v) {
    __hip_atomic_store(p + i, v, __ATOMIC_RELAXED, __HIP_MEMORY_SCOPE_AGENT);
}
__device__ inline void  pst_i(int* p, size_t i, int v) {
    __hip_atomic_store(p + i, v, __ATOMIC_RELAXED, __HIP_MEMORY_SCOPE_AGENT);
}
__device__ inline float pld_f(const float* p, size_t i) {
    return __hip_atomic_load(p + i, __ATOMIC_RELAXED, __HIP_MEMORY_SCOPE_AGENT);
}
__device__ inline int   pld_i(const int* p, size_t i) {
    return __hip_atomic_load(p + i, __ATOMIC_RELAXED, __HIP_MEMORY_SCOPE_AGENT);
}

// ---- stage chunk tiles [t0, t0+nt) into LDS (32-row tiles, 40 B row pitch) ----
// row g >= NG -> all-NaN halfs (MFMA output NaN; pass1 scrubs, pass2 mask kills)
__device__ inline void stage_sh(const float* __restrict__ gv, half4* lds4, int t0, int nt) {
    const int nrows = nt * 32;
    for (int lr = threadIdx.x; lr < nrows; lr += 256) {
        int g = t0 * 32 + lr;
        half4 s0, s1, s2, s3;
        if (g >= NG) {
            const _Float16 qn = (_Float16)__builtin_nanf("");
            s0 = (half4){qn, qn, qn, qn}; s1 = s0; s2 = s0; s3 = s0;
        } else {
            float x = gv[3 * g + 0], y = gv[3 * g + 1], z = gv[3 * g + 2];
            float n2 = x * x + y * y + z * z;
            float rn = __frsqrt_rn(fmaxf(n2, 1e-24f));
            float vx = x * rn, vy = y * rn, vz = z * rn;
            float x2 = vx * vx, y2 = vy * vy, z2 = vz * vz;
            const float c_m4 = (float)(0.75 * sqrt(35.0 / M_PI));
            const float c_m3 = (float)(0.75 * sqrt(35.0 / (2.0 * M_PI)));
            const float c_m2 = (float)(0.75 * sqrt(5.0 / M_PI));
            const float c_m1 = (float)(0.75 * sqrt(5.0 / (2.0 * M_PI)));
            const float c_0  = (float)((3.0 / 16.0) * sqrt(1.0 / M_PI));
            const float c_p2 = (float)((3.0 / 8.0) * sqrt(5.0 / M_PI));
            const float c_p4 = (float)((3.0 / 16.0) * sqrt(35.0 / M_PI));
            s0[0] = (_Float16)(c_m4 * vx * vy * (x2 - y2));
            s0[1] = (_Float16)(c_m3 * vy * vz * (3.0f * x2 - y2));
            s0[2] = (_Float16)(c_m2 * vx * vy * (7.0f * z2 - 1.0f));
            s0[3] = (_Float16)(c_m1 * vy * vz * (7.0f * z2 - 3.0f));
            s1[0] = (_Float16)(c_0  * (35.0f * z2 * z2 - 30.0f * z2 + 3.0f));
            s1[1] = (_Float16)(c_m1 * vx * vz * (7.0f * z2 - 3.0f));
            s1[2] = (_Float16)(c_p2 * (x2 - y2) * (7.0f * z2 - 1.0f));
            s1[3] = (_Float16)(c_m3 * vx * vz * (x2 - y2));
            s2[0] = (_Float16)(c_p4 * (x2 * x2 - 6.0f * x2 * y2 + y2 * y2));  // k=8
            s2[1] = (_Float16)x;   // k=9..11: raw grid vec (pass2 dot)
            s2[2] = (_Float16)y;
            s2[3] = (_Float16)z;
            s3 = (half4){0, 0, 0, 0};      // k=12..15 = 0
        }
        half4* row = lds4 + lr * 5;        // 5 half4 = 20 halfs = 40 B pitch (bank-friendly)
        row[0] = s0; row[1] = s1; row[2] = s2; row[3] = s3;
    }
}

// B-operand frag (f4 for one b column): B[k][col]: col=lane&31, k=(lane>>5)*8+j.
__device__ inline half8 make_bfrag(const float* __restrict__ f4, int b, int kh) {
    half8 a = {0, 0, 0, 0, 0, 0, 0, 0};
    const float* fr = f4 + (size_t)b * 9;
    if (kh == 0) {
#pragma unroll
        for (int j = 0; j < 8; ++j) a[j] = (_Float16)fr[j];
    } else {
        a[0] = (_Float16)fr[8];      // k=8
    }
    return a;
}

// merge (v2,g2) into (v,g) with numpy first-max semantics
__device__ inline void merge_vg(float& v, int& g, float v2, int g2) {
    bool take = (v2 > v) || (v2 == v && g2 < g);
    v = take ? v2 : v;
    g = take ? g2 : g;
}

// last-block detection: 20 consecutive u64 values hit each residue mod 20 exactly once,
// so (old % NCH == NCH-1) selects exactly ONE block per x regardless of the counter's
// (poisoned) starting value -> no init dispatch needed; survives replays/iterations.
__device__ inline bool last_block_flag(unsigned long long* ctr, int* flag) {
    __syncthreads();                 // drains each wave's vmcnt(0): all pst stores at LLC
    if (threadIdx.x == 0) {
        unsigned long long old = __hip_atomic_fetch_add(ctr + blockIdx.x, 1ull,
                                                        __ATOMIC_ACQ_REL,
                                                        __HIP_MEMORY_SCOPE_AGENT);
        *flag = ((unsigned)(old % NCH) == NCH - 1);
    }
    __syncthreads();
    return *flag != 0;
}

// ---------------- Kernel 1: pass-1 argmax + folded z-reduce (last block per x) ----------------
__global__ __launch_bounds__(256, 6) void k_pass1(const float* __restrict__ f4,
                                                  const float* __restrict__ gv,
                                                  float* __restrict__ P1v,
                                                  int* __restrict__ P1i,
                                                  float* __restrict__ zax,
                                                  unsigned long long* ctr1) {
    __shared__ half4 lds4[MAXTPC * 32 * 5];    // 20480 B -> 8 blocks/CU
    const int lane = threadIdx.x & 63;
    const int w = threadIdx.x >> 6;
    const int W = blockIdx.x * 4 + w;          // b-tile; b = 32W .. 32W+31
    const int n = lane & 31, kh = lane >> 5;
    const int chunk = blockIdx.y;
    const int b = W * 32 + n;

    const int t0 = (NGT * chunk) / NCH;
    const int t1 = (NGT * (chunk + 1)) / NCH;
    const int nt = t1 - t0;

    stage_sh(gv, lds4, t0, nt);
    const half8 bf = make_bfrag(f4, b, kh);
    __syncthreads();

    const floatx16 zero16 = {0.f,0.f,0.f,0.f, 0.f,0.f,0.f,0.f, 0.f,0.f,0.f,0.f, 0.f,0.f,0.f,0.f};
    const unsigned mskc = 0xFFFFFFF0u;
    float run = -INFINITY; int bt = 0;

    const half4* lp = lds4 + n * 5 + kh * 2;   // 8 halfs at k-offset kh*8
    half4 a0 = lp[0], a1 = lp[1]; lp += 32 * 5;

    for (int t = 0; t < nt - 1; ++t) {
        half4 b0 = lp[0], b1 = lp[1]; lp += 32 * 5;
        half8 af = __builtin_shufflevector(a0, a1, 0, 1, 2, 3, 4, 5, 6, 7);
        floatx16 c = __builtin_amdgcn_mfma_f32_32x32x16_f16(af, bf, zero16, 0, 0, 0);
        float p0,p1,p2,p3,p4,p5,p6,p7,p8,p9,p10,p11,p12,p13,p14,p15;
        PACKF(p0,  c[0],  "15"); PACKF(p1,  c[1],  "14");
        PACKF(p2,  c[2],  "13"); PACKF(p3,  c[3],  "12");
        PACKF(p4,  c[4],  "11"); PACKF(p5,  c[5],  "10");
        PACKF(p6,  c[6],  "9");  PACKF(p7,  c[7],  "8");
        PACKF(p8,  c[8],  "7");  PACKF(p9,  c[9],  "6");
        PACKF(p10, c[10], "5");  PACKF(p11, c[11], "4");
        PACKF(p12, c[12], "3");  PACKF(p13, c[13], "2");
        PACKF(p14, c[14], "1");  PACKF(p15, c[15], "0");
        float u0 = max3f(p0, p1, p2);
        float u1 = max3f(p3, p4, p5);
        float u2 = max3f(p6, p7, p8);
        float u3 = max3f(p9, p10, p11);
        float u4 = max3f(p12, p13, p14);
        float u5 = max3f(u0, u1, p15);
        float u6 = max3f(u2, u3, u4);
        float tm = fmaxf(u5, u6);
        bt = (tm > run) ? t : bt;
        run = fmaxf(run, tm);
        a0 = b0; a1 = b1;
    }
    {   // peeled last tile; tail-NaN scrub only where the tail lives (last chunk)
        half8 af = __builtin_shufflevector(a0, a1, 0, 1, 2, 3, 4, 5, 6, 7);
        floatx16 c = __builtin_amdgcn_mfma_f32_32x32x16_f16(af, bf, zero16, 0, 0, 0);
        if (chunk == NCH - 1) {
#pragma unroll
            for (int r = 0; r < 16; ++r) c[r] = fmaxf(c[r], -3.0e38f);
        }
        float p0,p1,p2,p3,p4,p5,p6,p7,p8,p9,p10,p11,p12,p13,p14,p15;
        PACKF(p0,  c[0],  "15"); PACKF(p1,  c[1],  "14");
        PACKF(p2,  c[2],  "13"); PACKF(p3,  c[3],  "12");
        PACKF(p4,  c[4],  "11"); PACKF(p5,  c[5],  "10");
        PACKF(p6,  c[6],  "9");  PACKF(p7,  c[7],  "8");
        PACKF(p8,  c[8],  "7");  PACKF(p9,  c[9],  "6");
        PACKF(p10, c[10], "5");  PACKF(p11, c[11], "4");
        PACKF(p12, c[12], "3");  PACKF(p13, c[13], "2");
        PACKF(p14, c[14], "1");  PACKF(p15, c[15], "0");
        float u0 = max3f(p0, p1, p2);
        float u1 = max3f(p3, p4, p5);
        float u2 = max3f(p6, p7, p8);
        float u3 = max3f(p9, p10, p11);
        float u4 = max3f(p12, p13, p14);
        float u5 = max3f(u0, u1, p15);
        float u6 = max3f(u2, u3, u4);
        float tm = fmaxf(u5, u6);
        bt = (tm > run) ? (nt - 1) : bt;
        run = fmaxf(run, tm);
    }
    // unpack: field = 15 - r  ->  r = 15 - (bits & 15); row = ROWMAP(r, kh)
    unsigned rb = __float_as_uint(run);
    int rwin = 15 - (int)(rb & 15u);
    int row = ROWMAP(rwin, kh);
    float v = __uint_as_float(rb & 0xFFFFFFF0u);
    int g = (t0 + bt) * 32 + row;
    merge_vg(v, g, __shfl_xor(v, 32), __shfl_xor(g, 32));
    if (kh == 0) {
        pst_f(P1v, (size_t)chunk * NB + b, v);
        pst_i(P1i, (size_t)chunk * NB + b, g);
    }

    // ---- folded z-reduce: exactly one block per x does it, once all 20 chunks stored ----
    if (last_block_flag(ctr1, (int*)lds4) && threadIdx.x < 128) {
        const int b2 = blockIdx.x * 128 + threadIdx.x;
        float bz = -INFINITY; int zi = 0;
#pragma unroll
        for (int cc = 0; cc < NCH; ++cc) {
            float vv = pld_f(P1v, (size_t)cc * NB + b2);
            int   ii = pld_i(P1i, (size_t)cc * NB + b2);
            merge_vg(bz, zi, vv, ii);
        }
        float4 z4 = {gv[3 * zi + 0], gv[3 * zi + 1], gv[3 * zi + 2], 0.f};
        *(float4*)(zax + 4 * (size_t)b2) = z4;   // plain store: consumed next dispatch
    }
}

// ---------------- Kernel 2: pass-2 masked argmax + folded finalize (last block per x) ----------------
__global__ __launch_bounds__(256, 6) void k_pass2(const float* __restrict__ f0,
                                                  const float* __restrict__ f4,
                                                  const float* __restrict__ gv,
                                                  const float* __restrict__ zax,
                                                  float* __restrict__ P2v,
                                                  int* __restrict__ P2i,
                                                  unsigned long long* ctr2,
                                                  float* __restrict__ out) {
    __shared__ half4 lds4[MAXTPC * 32 * 5];
    const int lane = threadIdx.x & 63;
    const int w = threadIdx.x >> 6;
    const int W = blockIdx.x * 4 + w;
    const int n = lane & 31, kh = lane >> 5;
    const int chunk = blockIdx.y;
    const int b = W * 32 + n;

    const int t0 = (NGT * chunk) / NCH;
    const int t1 = (NGT * (chunk + 1)) / NCH;
    const int nt = t1 - t0;

    stage_sh(gv, lds4, t0, nt);
    const half8 bf = make_bfrag(f4, b, kh);
    half8 df = {0, 0, 0, 0, 0, 0, 0, 0};
    if (kh == 1) {                           // z_b at k=9,10,11 -> j=1..3
        const float* zp = zax + 4 * (size_t)b;
        df[1] = (_Float16)zp[0];
        df[2] = (_Float16)zp[1];
        df[3] = (_Float16)zp[2];
    }
    __syncthreads();

    const floatx16 zero16 = {0.f,0.f,0.f,0.f, 0.f,0.f,0.f,0.f, 0.f,0.f,0.f,0.f, 0.f,0.f,0.f,0.f};
    const unsigned mskc = 0xFFFFFFF0u;
    const float ninf = -INFINITY;
    const float lim = 0.2f;
    float run = -INFINITY; int bt = 0;

    const half4* lp = lds4 + n * 5 + kh * 2;
    half4 a0 = lp[0], a1 = lp[1]; lp += 32 * 5;

    for (int t = 0; t < nt; ++t) {
        half4 b0, b1;
        if (t < nt - 1) { b0 = lp[0]; b1 = lp[1]; lp += 32 * 5; }
        half8 af = __builtin_shufflevector(a0, a1, 0, 1, 2, 3, 4, 5, 6, 7);
        floatx16 cs = __builtin_amdgcn_mfma_f32_32x32x16_f16(af, bf, zero16, 0, 0, 0);
        floatx16 cd = __builtin_amdgcn_mfma_f32_32x32x16_f16(af, df, zero16, 0, 0, 0);
        // per reg: pack row-field into cs, then mask by |dot|<0.2 (NaN dot -> -inf, kills tail)
        float q;
        float s0,s1,s2,s3,s4,s5,s6,s7,s8,s9,s10,s11,s12,s13,s14,s15;
        PACKF(q, cs[0],  "15"); s0  = (fabsf(cd[0])  < lim) ? q : ninf;
        PACKF(q, cs[1],  "14"); s1  = (fabsf(cd[1])  < lim) ? q : ninf;
        PACKF(q, cs[2],  "13"); s2  = (fabsf(cd[2])  < lim) ? q : ninf;
        PACKF(q, cs[3],  "12"); s3  = (fabsf(cd[3])  < lim) ? q : ninf;
        PACKF(q, cs[4],  "11"); s4  = (fabsf(cd[4])  < lim) ? q : ninf;
        PACKF(q, cs[5],  "10"); s5  = (fabsf(cd[5])  < lim) ? q : ninf;
        PACKF(q, cs[6],  "9");  s6  = (fabsf(cd[6])  < lim) ? q : ninf;
        PACKF(q, cs[7],  "8");  s7  = (fabsf(cd[7])  < lim) ? q : ninf;
        PACKF(q, cs[8],  "7");  s8  = (fabsf(cd[8])  < lim) ? q : ninf;
        PACKF(q, cs[9],  "6");  s9  = (fabsf(cd[9])  < lim) ? q : ninf;
        PACKF(q, cs[10], "5");  s10 = (fabsf(cd[10]) < lim) ? q : ninf;
        PACKF(q, cs[11], "4");  s11 = (fabsf(cd[11]) < lim) ? q : ninf;
        PACKF(q, cs[12], "3");  s12 = (fabsf(cd[12]) < lim) ? q : ninf;
        PACKF(q, cs[13], "2");  s13 = (fabsf(cd[13]) < lim) ? q : ninf;
        PACKF(q, cs[14], "1");  s14 = (fabsf(cd[14]) < lim) ? q : ninf;
        PACKF(q, cs[15], "0");  s15 = (fabsf(cd[15]) < lim) ? q : ninf;
        float u0 = max3f(s0, s1, s2);
        float u1 = max3f(s3, s4, s5);
        float u2 = max3f(s6, s7, s8);
        float u3 = max3f(s9, s10, s11);
        float u4 = max3f(s12, s13, s14);
        float u5 = max3f(u0, u1, s15);
        float u6 = max3f(u2, u3, u4);
        float tm = fmaxf(u5, u6);
        bt = (tm > run) ? t : bt;
        run = fmaxf(run, tm);
        a0 = b0; a1 = b1;
    }
    unsigned rb = __float_as_uint(run);
    int rwin = 15 - (int)(rb & 15u);
    int row = ROWMAP(rwin, kh);
    float v = __uint_as_float(rb & 0xFFFFFFF0u);
    int g = (t0 + bt) * 32 + row;
    merge_vg(v, g, __shfl_xor(v, 32), __shfl_xor(g, 32));
    if (kh == 0) {
        pst_f(P2v, (size_t)chunk * NB + b, v);
        pst_i(P2i, (size_t)chunk * NB + b, g);
    }

    // ---- folded finalize: one block per x merges P2 and writes quaternion + boundary map ----
    if (last_block_flag(ctr2, (int*)lds4) && threadIdx.x < 128) {
        const int b2 = blockIdx.x * 128 + threadIdx.x;
        float bx = -INFINITY; int xi = 0;
#pragma unroll
        for (int cc = 0; cc < NCH; ++cc) {
            float vv = pld_f(P2v, (size_t)cc * NB + b2);
            int   ii = pld_i(P2i, (size_t)cc * NB + b2);
            merge_vg(bx, xi, vv, ii);
        }
        const float* zp = zax + 4 * (size_t)b2;
        float zr0 = zp[0], zr1 = zp[1], zr2 = zp[2];
        float xr0 = gv[3 * xi], xr1 = gv[3 * xi + 1], xr2 = gv[3 * xi + 2];
        float zn = sqrtf(zr0 * zr0 + zr1 * zr1 + zr2 * zr2);
        float zd = fmaxf(zn, 1e-12f);
        float z0 = zr0 / zd, z1 = zr1 / zd, z2 = zr2 / zd;
        float pr = xr0 * z0 + xr1 * z1 + xr2 * z2;
        float ux = xr0 - pr * z0, uy = xr1 - pr * z1, uz = xr2 - pr * z2;
        float xn = sqrtf(ux * ux + uy * uy + uz * uz);
        float xd = fmaxf(xn, 1e-12f);
        float x0 = ux / xd, x1 = uy / xd, x2 = uz / xd;
        float y0 = z1 * x2 - z2 * x1;
        float y1 = z2 * x0 - z0 * x2;
        float y2 = z0 * x1 - z1 * x0;
        float m00 = x0, m01 = y0, m02 = z0;
        float m10 = x1, m11 = y1, m12 = z1;
        float m20 = x2, m21 = y2, m22 = z2;
        float q0 = sqrtf(fmaxf(1.0f + m00 + m11 + m22, 0.0f));
        float q1 = sqrtf(fmaxf(1.0f + m00 - m11 - m22, 0.0f));
        float q2 = sqrtf(fmaxf(1.0f - m00 + m11 - m22, 0.0f));
        float q3 = sqrtf(fmaxf(1.0f - m00 - m11 + m22, 0.0f));
        int bq = 0; float qb = q0;
        if (q1 > qb) { qb = q1; bq = 1; }
        if (q2 > qb) { qb = q2; bq = 2; }
        if (q3 > qb) { qb = q3; bq = 3; }
        float dd = 2.0f * fmaxf(qb, 0.1f);
        float wq, qx, qy, qz;
        if (bq == 0)      { wq = q0 * q0;  qx = m21 - m12; qy = m02 - m20; qz = m10 - m01; }
        else if (bq == 1) { wq = m21 - m12; qx = q1 * q1;  qy = m10 + m01; qz = m02 + m20; }
        else if (bq == 2) { wq = m02 - m20; qx = m10 + m01; qy = q2 * q2;  qz = m12 + m21; }
        else              { wq = m10 - m01; qx = m20 + m02; qy = m21 + m12; qz = q3 * q3; }
        out[b2 * 4 + 0] = wq / dd;
        out[b2 * 4 + 1] = qx / dd;
        out[b2 * 4 + 2] = qy / dd;
        out[b2 * 4 + 3] = qz / dd;
        out[4 * NB + b2] = f0[b2] * (float)(180.0 / M_PI);
    }
}

extern "C" void kernel_launch(void* const* d_in, const int* in_sizes, int n_in,
                              void* d_out, int out_size, void* d_ws, size_t ws_size,
                              hipStream_t stream) {
    const float* f0 = (const float*)d_in[0];   // [16384, 1]
    const float* f4 = (const float*)d_in[2];   // [16384, 9]
    const float* gv = (const float*)d_in[4];   // [10000, 3]
    float* out = (float*)d_out;
    (void)in_sizes; (void)n_in; (void)out_size; (void)ws_size;

    // ws layout (1.5 MB stride): P1v | P1i | P2v | P2i | zax | ctr1(1KB) | ctr2(1KB)
    char* W = (char*)d_ws;
    float* P1v = (float*)(W + 0);
    int*   P1i = (int*)(W + 0x180000);
    float* P2v = (float*)(W + 2 * 0x180000);
    int*   P2i = (int*)(W + 3 * 0x180000);
    float* zax = (float*)(W + 4 * 0x180000);                    // [NB][4] floats
    unsigned long long* ctr1 = (unsigned long long*)(W + 5 * 0x180000);
    unsigned long long* ctr2 = (unsigned long long*)(W + 5 * 0x180000 + 4096);
    // counters are NOT initialized: last-block test is (old % NCH == NCH-1), which
    // selects exactly one block per x for any starting value (20 consecutive u64s).

    // 512 b-tiles / 4 waves = 128 blocks x; 20 chunks y = 2560 blocks, 8/CU resident
    dim3 grid2(128, NCH);
    k_pass1<<<grid2, 256, 0, stream>>>(f4, gv, P1v, P1i, zax, ctr1);
    k_pass2<<<grid2, 256, 0, stream>>>(f0, f4, gv, zax, P2v, P2i, ctr2, out);
}

// Round 9
// 101.223 us; speedup vs baseline: 1.6018x; 1.6018x over previous
//
#include <hip/hip_runtime.h>
#include <math.h>
#include <stdint.h>

#define NB 16384
#define NG 10000
#define NGT 313           // ceil(NG/32) g-tiles of 32; tail rows NaN -> scrubbed in peeled iter
#define NCH 20            // g-chunks; chunk c covers tiles [NGT*c/NCH, NGT*(c+1)/NCH)
#define MAXTPC 16         // max tiles/chunk: 16 * 32 rows * 40 B = 20480 B LDS -> 8 blocks/CU

typedef _Float16 half4 __attribute__((ext_vector_type(4)));
typedef _Float16 half8 __attribute__((ext_vector_type(8)));
typedef float    floatx16 __attribute__((ext_vector_type(16)));

// C/D row map for 32x32x16: row = (r&3) + 8*(r>>2) + 4*kh
#define ROWMAP(r, kh) (((r) & 3) + 8 * ((r) >> 2) + 4 * (kh))

__device__ inline float max3f(float a, float b, float c) {
    float d;
    asm("v_max3_f32 %0, %1, %2, %3" : "=v"(d) : "v"(a), "v"(b), "v"(c));
    return d;
}

// p = bitcast( (bits(c) & 0xFFFFFFF0) | F )  -- pack 4-bit field into low mantissa
#define PACKF(p_, c_, F_) \
    asm("v_and_or_b32 %0, %1, %2, " F_ : "=v"(p_) : "v"(c_), "s"(mskc))

// ---- cross-block data through the coherent point (LLC), r2-proven helpers ----
// RELAXED ONLY: agent-scope acquire/release would writeback+invalidate the whole
// per-XCD L2 per op (r8 regression: pass2 58us, FETCH 2.5x, VALUBusy 80->34).
__device__ inline void  pst_f(float* p, size_t i, float v) {
    __hip_atomic_store(p + i, v, __ATOMIC_RELAXED, __HIP_MEMORY_SCOPE_AGENT);
}
__device__ inline void  pst_i(int* p, size_t i, int v) {
    __hip_atomic_store(p + i, v, __ATOMIC_RELAXED, __HIP_MEMORY_SCOPE_AGENT);
}
__device__ inline float pld_f(const float* p, size_t i) {
    return __hip_atomic_load(p + i, __ATOMIC_RELAXED, __HIP_MEMORY_SCOPE_AGENT);
}
__device__ inline int   pld_i(const int* p, size_t i) {
    return __hip_atomic_load(p + i, __ATOMIC_RELAXED, __HIP_MEMORY_SCOPE_AGENT);
}

// ---- stage chunk tiles [t0, t0+nt) into LDS (32-row tiles, 40 B row pitch) ----
// row g >= NG -> all-NaN halfs (MFMA output NaN; pass1 scrubs, pass2 mask kills)
__device__ inline void stage_sh(const float* __restrict__ gv, half4* lds4, int t0, int nt) {
    const int nrows = nt * 32;
    for (int lr = threadIdx.x; lr < nrows; lr += 256) {
        int g = t0 * 32 + lr;
        half4 s0, s1, s2, s3;
        if (g >= NG) {
            const _Float16 qn = (_Float16)__builtin_nanf("");
            s0 = (half4){qn, qn, qn, qn}; s1 = s0; s2 = s0; s3 = s0;
        } else {
            float x = gv[3 * g + 0], y = gv[3 * g + 1], z = gv[3 * g + 2];
            float n2 = x * x + y * y + z * z;
            float rn = __frsqrt_rn(fmaxf(n2, 1e-24f));
            float vx = x * rn, vy = y * rn, vz = z * rn;
            float x2 = vx * vx, y2 = vy * vy, z2 = vz * vz;
            const float c_m4 = (float)(0.75 * sqrt(35.0 / M_PI));
            const float c_m3 = (float)(0.75 * sqrt(35.0 / (2.0 * M_PI)));
            const float c_m2 = (float)(0.75 * sqrt(5.0 / M_PI));
            const float c_m1 = (float)(0.75 * sqrt(5.0 / (2.0 * M_PI)));
            const float c_0  = (float)((3.0 / 16.0) * sqrt(1.0 / M_PI));
            const float c_p2 = (float)((3.0 / 8.0) * sqrt(5.0 / M_PI));
            const float c_p4 = (float)((3.0 / 16.0) * sqrt(35.0 / M_PI));
            s0[0] = (_Float16)(c_m4 * vx * vy * (x2 - y2));
            s0[1] = (_Float16)(c_m3 * vy * vz * (3.0f * x2 - y2));
            s0[2] = (_Float16)(c_m2 * vx * vy * (7.0f * z2 - 1.0f));
            s0[3] = (_Float16)(c_m1 * vy * vz * (7.0f * z2 - 3.0f));
            s1[0] = (_Float16)(c_0  * (35.0f * z2 * z2 - 30.0f * z2 + 3.0f));
            s1[1] = (_Float16)(c_m1 * vx * vz * (7.0f * z2 - 3.0f));
            s1[2] = (_Float16)(c_p2 * (x2 - y2) * (7.0f * z2 - 1.0f));
            s1[3] = (_Float16)(c_m3 * vx * vz * (x2 - y2));
            s2[0] = (_Float16)(c_p4 * (x2 * x2 - 6.0f * x2 * y2 + y2 * y2));  // k=8
            s2[1] = (_Float16)x;   // k=9..11: raw grid vec (pass2 dot)
            s2[2] = (_Float16)y;
            s2[3] = (_Float16)z;
            s3 = (half4){0, 0, 0, 0};      // k=12..15 = 0
        }
        half4* row = lds4 + lr * 5;        // 5 half4 = 20 halfs = 40 B pitch (bank-friendly)
        row[0] = s0; row[1] = s1; row[2] = s2; row[3] = s3;
    }
}

// B-operand frag (f4 for one b column): B[k][col]: col=lane&31, k=(lane>>5)*8+j.
__device__ inline half8 make_bfrag(const float* __restrict__ f4, int b, int kh) {
    half8 a = {0, 0, 0, 0, 0, 0, 0, 0};
    const float* fr = f4 + (size_t)b * 9;
    if (kh == 0) {
#pragma unroll
        for (int j = 0; j < 8; ++j) a[j] = (_Float16)fr[j];
    } else {
        a[0] = (_Float16)fr[8];      // k=8
    }
    return a;
}

// merge (v2,g2) into (v,g) with numpy first-max semantics
__device__ inline void merge_vg(float& v, int& g, float v2, int g2) {
    bool take = (v2 > v) || (v2 == v && g2 < g);
    v = take ? v2 : v;
    g = take ? g2 : g;
}

// last-block detection: 20 consecutive u64 values hit each residue mod 20 exactly once,
// so (old % NCH == NCH-1) selects exactly ONE block per x regardless of the counter's
// (poisoned) starting value -> no init dispatch needed; survives replays/iterations.
// RELAXED fetch_add: __syncthreads() drains vmcnt(0) so this block's pst stores are
// ack'd at the LLC before the bump; program order does the rest. No L2 flush.
__device__ inline bool last_block_flag(unsigned long long* ctr, int* flag) {
    __syncthreads();
    if (threadIdx.x == 0) {
        unsigned long long old = __hip_atomic_fetch_add(ctr + blockIdx.x, 1ull,
                                                        __ATOMIC_RELAXED,
                                                        __HIP_MEMORY_SCOPE_AGENT);
        *flag = ((unsigned)(old % NCH) == NCH - 1);
    }
    __syncthreads();
    return *flag != 0;
}

// ---------------- Kernel 1: pass-1 argmax + folded z-reduce (last block per x) ----------------
__global__ __launch_bounds__(256, 6) void k_pass1(const float* __restrict__ f4,
                                                  const float* __restrict__ gv,
                                                  float* __restrict__ P1v,
                                                  int* __restrict__ P1i,
                                                  float* __restrict__ zax,
                                                  unsigned long long* ctr1) {
    __shared__ half4 lds4[MAXTPC * 32 * 5];    // 20480 B -> 8 blocks/CU
    const int lane = threadIdx.x & 63;
    const int w = threadIdx.x >> 6;
    const int W = blockIdx.x * 4 + w;          // b-tile; b = 32W .. 32W+31
    const int n = lane & 31, kh = lane >> 5;
    const int chunk = blockIdx.y;
    const int b = W * 32 + n;

    const int t0 = (NGT * chunk) / NCH;
    const int t1 = (NGT * (chunk + 1)) / NCH;
    const int nt = t1 - t0;

    stage_sh(gv, lds4, t0, nt);
    const half8 bf = make_bfrag(f4, b, kh);
    __syncthreads();

    const floatx16 zero16 = {0.f,0.f,0.f,0.f, 0.f,0.f,0.f,0.f, 0.f,0.f,0.f,0.f, 0.f,0.f,0.f,0.f};
    const unsigned mskc = 0xFFFFFFF0u;
    float run = -INFINITY; int bt = 0;

    const half4* lp = lds4 + n * 5 + kh * 2;   // 8 halfs at k-offset kh*8
    half4 a0 = lp[0], a1 = lp[1]; lp += 32 * 5;

    for (int t = 0; t < nt - 1; ++t) {
        half4 b0 = lp[0], b1 = lp[1]; lp += 32 * 5;
        half8 af = __builtin_shufflevector(a0, a1, 0, 1, 2, 3, 4, 5, 6, 7);
        floatx16 c = __builtin_amdgcn_mfma_f32_32x32x16_f16(af, bf, zero16, 0, 0, 0);
        float p0,p1,p2,p3,p4,p5,p6,p7,p8,p9,p10,p11,p12,p13,p14,p15;
        PACKF(p0,  c[0],  "15"); PACKF(p1,  c[1],  "14");
        PACKF(p2,  c[2],  "13"); PACKF(p3,  c[3],  "12");
        PACKF(p4,  c[4],  "11"); PACKF(p5,  c[5],  "10");
        PACKF(p6,  c[6],  "9");  PACKF(p7,  c[7],  "8");
        PACKF(p8,  c[8],  "7");  PACKF(p9,  c[9],  "6");
        PACKF(p10, c[10], "5");  PACKF(p11, c[11], "4");
        PACKF(p12, c[12], "3");  PACKF(p13, c[13], "2");
        PACKF(p14, c[14], "1");  PACKF(p15, c[15], "0");
        float u0 = max3f(p0, p1, p2);
        float u1 = max3f(p3, p4, p5);
        float u2 = max3f(p6, p7, p8);
        float u3 = max3f(p9, p10, p11);
        float u4 = max3f(p12, p13, p14);
        float u5 = max3f(u0, u1, p15);
        float u6 = max3f(u2, u3, u4);
        float tm = fmaxf(u5, u6);
        bt = (tm > run) ? t : bt;
        run = fmaxf(run, tm);
        a0 = b0; a1 = b1;
    }
    {   // peeled last tile; tail-NaN scrub only where the tail lives (last chunk)
        half8 af = __builtin_shufflevector(a0, a1, 0, 1, 2, 3, 4, 5, 6, 7);
        floatx16 c = __builtin_amdgcn_mfma_f32_32x32x16_f16(af, bf, zero16, 0, 0, 0);
        if (chunk == NCH - 1) {
#pragma unroll
            for (int r = 0; r < 16; ++r) c[r] = fmaxf(c[r], -3.0e38f);
        }
        float p0,p1,p2,p3,p4,p5,p6,p7,p8,p9,p10,p11,p12,p13,p14,p15;
        PACKF(p0,  c[0],  "15"); PACKF(p1,  c[1],  "14");
        PACKF(p2,  c[2],  "13"); PACKF(p3,  c[3],  "12");
        PACKF(p4,  c[4],  "11"); PACKF(p5,  c[5],  "10");
        PACKF(p6,  c[6],  "9");  PACKF(p7,  c[7],  "8");
        PACKF(p8,  c[8],  "7");  PACKF(p9,  c[9],  "6");
        PACKF(p10, c[10], "5");  PACKF(p11, c[11], "4");
        PACKF(p12, c[12], "3");  PACKF(p13, c[13], "2");
        PACKF(p14, c[14], "1");  PACKF(p15, c[15], "0");
        float u0 = max3f(p0, p1, p2);
        float u1 = max3f(p3, p4, p5);
        float u2 = max3f(p6, p7, p8);
        float u3 = max3f(p9, p10, p11);
        float u4 = max3f(p12, p13, p14);
        float u5 = max3f(u0, u1, p15);
        float u6 = max3f(u2, u3, u4);
        float tm = fmaxf(u5, u6);
        bt = (tm > run) ? (nt - 1) : bt;
        run = fmaxf(run, tm);
    }
    // unpack: field = 15 - r  ->  r = 15 - (bits & 15); row = ROWMAP(r, kh)
    unsigned rb = __float_as_uint(run);
    int rwin = 15 - (int)(rb & 15u);
    int row = ROWMAP(rwin, kh);
    float v = __uint_as_float(rb & 0xFFFFFFF0u);
    int g = (t0 + bt) * 32 + row;
    merge_vg(v, g, __shfl_xor(v, 32), __shfl_xor(g, 32));
    if (kh == 0) {
        pst_f(P1v, (size_t)chunk * NB + b, v);
        pst_i(P1i, (size_t)chunk * NB + b, g);
    }

    // ---- folded z-reduce: exactly one block per x does it, once all 20 chunks stored ----
    if (last_block_flag(ctr1, (int*)lds4) && threadIdx.x < 128) {
        const int b2 = blockIdx.x * 128 + threadIdx.x;
        float bz = -INFINITY; int zi = 0;
#pragma unroll
        for (int cc = 0; cc < NCH; ++cc) {
            float vv = pld_f(P1v, (size_t)cc * NB + b2);
            int   ii = pld_i(P1i, (size_t)cc * NB + b2);
            merge_vg(bz, zi, vv, ii);
        }
        float4 z4 = {gv[3 * zi + 0], gv[3 * zi + 1], gv[3 * zi + 2], 0.f};
        *(float4*)(zax + 4 * (size_t)b2) = z4;   // plain store: consumed next dispatch
    }
}

// ---------------- Kernel 2: pass-2 masked argmax + folded finalize (last block per x) ----------------
__global__ __launch_bounds__(256, 6) void k_pass2(const float* __restrict__ f0,
                                                  const float* __restrict__ f4,
                                                  const float* __restrict__ gv,
                                                  const float* __restrict__ zax,
                                                  float* __restrict__ P2v,
                                                  int* __restrict__ P2i,
                                                  unsigned long long* ctr2,
                                                  float* __restrict__ out) {
    __shared__ half4 lds4[MAXTPC * 32 * 5];
    const int lane = threadIdx.x & 63;
    const int w = threadIdx.x >> 6;
    const int W = blockIdx.x * 4 + w;
    const int n = lane & 31, kh = lane >> 5;
    const int chunk = blockIdx.y;
    const int b = W * 32 + n;

    const int t0 = (NGT * chunk) / NCH;
    const int t1 = (NGT * (chunk + 1)) / NCH;
    const int nt = t1 - t0;

    stage_sh(gv, lds4, t0, nt);
    const half8 bf = make_bfrag(f4, b, kh);
    half8 df = {0, 0, 0, 0, 0, 0, 0, 0};
    if (kh == 1) {                           // z_b at k=9,10,11 -> j=1..3
        const float* zp = zax + 4 * (size_t)b;
        df[1] = (_Float16)zp[0];
        df[2] = (_Float16)zp[1];
        df[3] = (_Float16)zp[2];
    }
    __syncthreads();

    const floatx16 zero16 = {0.f,0.f,0.f,0.f, 0.f,0.f,0.f,0.f, 0.f,0.f,0.f,0.f, 0.f,0.f,0.f,0.f};
    const unsigned mskc = 0xFFFFFFF0u;
    const float ninf = -INFINITY;
    const float lim = 0.2f;
    float run = -INFINITY; int bt = 0;

    const half4* lp = lds4 + n * 5 + kh * 2;
    half4 a0 = lp[0], a1 = lp[1]; lp += 32 * 5;

    for (int t = 0; t < nt; ++t) {
        half4 b0, b1;
        if (t < nt - 1) { b0 = lp[0]; b1 = lp[1]; lp += 32 * 5; }
        half8 af = __builtin_shufflevector(a0, a1, 0, 1, 2, 3, 4, 5, 6, 7);
        floatx16 cs = __builtin_amdgcn_mfma_f32_32x32x16_f16(af, bf, zero16, 0, 0, 0);
        floatx16 cd = __builtin_amdgcn_mfma_f32_32x32x16_f16(af, df, zero16, 0, 0, 0);
        // per reg: pack row-field into cs, then mask by |dot|<0.2 (NaN dot -> -inf, kills tail)
        float q;
        float s0,s1,s2,s3,s4,s5,s6,s7,s8,s9,s10,s11,s12,s13,s14,s15;
        PACKF(q, cs[0],  "15"); s0  = (fabsf(cd[0])  < lim) ? q : ninf;
        PACKF(q, cs[1],  "14"); s1  = (fabsf(cd[1])  < lim) ? q : ninf;
        PACKF(q, cs[2],  "13"); s2  = (fabsf(cd[2])  < lim) ? q : ninf;
        PACKF(q, cs[3],  "12"); s3  = (fabsf(cd[3])  < lim) ? q : ninf;
        PACKF(q, cs[4],  "11"); s4  = (fabsf(cd[4])  < lim) ? q : ninf;
        PACKF(q, cs[5],  "10"); s5  = (fabsf(cd[5])  < lim) ? q : ninf;
        PACKF(q, cs[6],  "9");  s6  = (fabsf(cd[6])  < lim) ? q : ninf;
        PACKF(q, cs[7],  "8");  s7  = (fabsf(cd[7])  < lim) ? q : ninf;
        PACKF(q, cs[8],  "7");  s8  = (fabsf(cd[8])  < lim) ? q : ninf;
        PACKF(q, cs[9],  "6");  s9  = (fabsf(cd[9])  < lim) ? q : ninf;
        PACKF(q, cs[10], "5");  s10 = (fabsf(cd[10]) < lim) ? q : ninf;
        PACKF(q, cs[11], "4");  s11 = (fabsf(cd[11]) < lim) ? q : ninf;
        PACKF(q, cs[12], "3");  s12 = (fabsf(cd[12]) < lim) ? q : ninf;
        PACKF(q, cs[13], "2");  s13 = (fabsf(cd[13]) < lim) ? q : ninf;
        PACKF(q, cs[14], "1");  s14 = (fabsf(cd[14]) < lim) ? q : ninf;
        PACKF(q, cs[15], "0");  s15 = (fabsf(cd[15]) < lim) ? q : ninf;
        float u0 = max3f(s0, s1, s2);
        float u1 = max3f(s3, s4, s5);
        float u2 = max3f(s6, s7, s8);
        float u3 = max3f(s9, s10, s11);
        float u4 = max3f(s12, s13, s14);
        float u5 = max3f(u0, u1, s15);
        float u6 = max3f(u2, u3, u4);
        float tm = fmaxf(u5, u6);
        bt = (tm > run) ? t : bt;
        run = fmaxf(run, tm);
        a0 = b0; a1 = b1;
    }
    unsigned rb = __float_as_uint(run);
    int rwin = 15 - (int)(rb & 15u);
    int row = ROWMAP(rwin, kh);
    float v = __uint_as_float(rb & 0xFFFFFFF0u);
    int g = (t0 + bt) * 32 + row;
    merge_vg(v, g, __shfl_xor(v, 32), __shfl_xor(g, 32));
    if (kh == 0) {
        pst_f(P2v, (size_t)chunk * NB + b, v);
        pst_i(P2i, (size_t)chunk * NB + b, g);
    }

    // ---- folded finalize: one block per x merges P2 and writes quaternion + boundary map ----
    if (last_block_flag(ctr2, (int*)lds4) && threadIdx.x < 128) {
        const int b2 = blockIdx.x * 128 + threadIdx.x;
        float bx = -INFINITY; int xi = 0;
#pragma unroll
        for (int cc = 0; cc < NCH; ++cc) {
            float vv = pld_f(P2v, (size_t)cc * NB + b2);
            int   ii = pld_i(P2i, (size_t)cc * NB + b2);
            merge_vg(bx, xi, vv, ii);
        }
        const float* zp = zax + 4 * (size_t)b2;
        float zr0 = zp[0], zr1 = zp[1], zr2 = zp[2];
        float xr0 = gv[3 * xi], xr1 = gv[3 * xi + 1], xr2 = gv[3 * xi + 2];
        float zn = sqrtf(zr0 * zr0 + zr1 * zr1 + zr2 * zr2);
        float zd = fmaxf(zn, 1e-12f);
        float z0 = zr0 / zd, z1 = zr1 / zd, z2 = zr2 / zd;
        float pr = xr0 * z0 + xr1 * z1 + xr2 * z2;
        float ux = xr0 - pr * z0, uy = xr1 - pr * z1, uz = xr2 - pr * z2;
        float xn = sqrtf(ux * ux + uy * uy + uz * uz);
        float xd = fmaxf(xn, 1e-12f);
        float x0 = ux / xd, x1 = uy / xd, x2 = uz / xd;
        float y0 = z1 * x2 - z2 * x1;
        float y1 = z2 * x0 - z0 * x2;
        float y2 = z0 * x1 - z1 * x0;
        float m00 = x0, m01 = y0, m02 = z0;
        float m10 = x1, m11 = y1, m12 = z1;
        float m20 = x2, m21 = y2, m22 = z2;
        float q0 = sqrtf(fmaxf(1.0f + m00 + m11 + m22, 0.0f));
        float q1 = sqrtf(fmaxf(1.0f + m00 - m11 - m22, 0.0f));
        float q2 = sqrtf(fmaxf(1.0f - m00 + m11 - m22, 0.0f));
        float q3 = sqrtf(fmaxf(1.0f - m00 - m11 + m22, 0.0f));
        int bq = 0; float qb = q0;
        if (q1 > qb) { qb = q1; bq = 1; }
        if (q2 > qb) { qb = q2; bq = 2; }
        if (q3 > qb) { qb = q3; bq = 3; }
        float dd = 2.0f * fmaxf(qb, 0.1f);
        float wq, qx, qy, qz;
        if (bq == 0)      { wq = q0 * q0;  qx = m21 - m12; qy = m02 - m20; qz = m10 - m01; }
        else if (bq == 1) { wq = m21 - m12; qx = q1 * q1;  qy = m10 + m01; qz = m02 + m20; }
        else if (bq == 2) { wq = m02 - m20; qx = m10 + m01; qy = q2 * q2;  qz = m12 + m21; }
        else              { wq = m10 - m01; qx = m20 + m02; qy = m21 + m12; qz = q3 * q3; }
        out[b2 * 4 + 0] = wq / dd;
        out[b2 * 4 + 1] = qx / dd;
        out[b2 * 4 + 2] = qy / dd;
        out[b2 * 4 + 3] = qz / dd;
        out[4 * NB + b2] = f0[b2] * (float)(180.0 / M_PI);
    }
}

extern "C" void kernel_launch(void* const* d_in, const int* in_sizes, int n_in,
                              void* d_out, int out_size, void* d_ws, size_t ws_size,
                              hipStream_t stream) {
    const float* f0 = (const float*)d_in[0];   // [16384, 1]
    const float* f4 = (const float*)d_in[2];   // [16384, 9]
    const float* gv = (const float*)d_in[4];   // [10000, 3]
    float* out = (float*)d_out;
    (void)in_sizes; (void)n_in; (void)out_size; (void)ws_size;

    // ws layout (1.5 MB stride): P1v | P1i | P2v | P2i | zax | ctr1(1KB) | ctr2(1KB)
    char* W = (char*)d_ws;
    float* P1v = (float*)(W + 0);
    int*   P1i = (int*)(W + 0x180000);
    float* P2v = (float*)(W + 2 * 0x180000);
    int*   P2i = (int*)(W + 3 * 0x180000);
    float* zax = (float*)(W + 4 * 0x180000);                    // [NB][4] floats
    unsigned long long* ctr1 = (unsigned long long*)(W + 5 * 0x180000);
    unsigned long long* ctr2 = (unsigned long long*)(W + 5 * 0x180000 + 4096);
    // counters are NOT initialized: last-block test is (old % NCH == NCH-1), which
    // selects exactly one block per x for any starting value (20 consecutive u64s).

    // 512 b-tiles / 4 waves = 128 blocks x; 20 chunks y = 2560 blocks, 8/CU resident
    dim3 grid2(128, NCH);
    k_pass1<<<grid2, 256, 0, stream>>>(f4, gv, P1v, P1i, zax, ctr1);
    k_pass2<<<grid2, 256, 0, stream>>>(f0, f4, gv, zax, P2v, P2i, ctr2, out);
}

// Round 10
// 97.160 us; speedup vs baseline: 1.6688x; 1.0418x over previous
//
#include <hip/hip_runtime.h>
#include <math.h>
#include <stdint.h>

#define NB 16384
#define NG 10000
#define NGT 313           // ceil(NG/32) g-tiles of 32; tail rows NaN -> scrubbed in last tile
#define NCH 20            // g-chunks; chunk c covers tiles [NGT*c/NCH, NGT*(c+1)/NCH)
#define MAXTPC 16         // max tiles/chunk: 16 * 32 rows * 40 B = 20480 B LDS -> 8 blocks/CU

typedef _Float16 half4 __attribute__((ext_vector_type(4)));
typedef _Float16 half8 __attribute__((ext_vector_type(8)));
typedef float    floatx16 __attribute__((ext_vector_type(16)));

// C/D row map for 32x32x16: row = (r&3) + 8*(r>>2) + 4*kh   (monotone in r for fixed kh)
#define ROWMAP(r, kh) (((r) & 3) + 8 * ((r) >> 2) + 4 * (kh))

__device__ inline float max3f(float a, float b, float c) {
    float d;
    asm("v_max3_f32 %0, %1, %2, %3" : "=v"(d) : "v"(a), "v"(b), "v"(c));
    return d;
}

// 16 -> 1 max tree on raw values: 7 x v_max3 + 1 x v_max
__device__ inline float tree16(const floatx16& c) {
    float u0 = max3f(c[0],  c[1],  c[2]);
    float u1 = max3f(c[3],  c[4],  c[5]);
    float u2 = max3f(c[6],  c[7],  c[8]);
    float u3 = max3f(c[9],  c[10], c[11]);
    float u4 = max3f(c[12], c[13], c[14]);
    float u5 = max3f(u0, u1, c[15]);
    float u6 = max3f(u2, u3, u4);
    return fmaxf(u5, u6);
}

// ---- cross-block data through the coherent point (LLC), r2/r9-proven helpers ----
// RELAXED ONLY: agent-scope acquire/release writebacks+invalidates the whole per-XCD
// L2 per op (r8 regression: pass2 58us, FETCH 2.5x, VALUBusy 80->34).
__device__ inline void  pst_f(float* p, size_t i, float v) {
    __hip_atomic_store(p + i, v, __ATOMIC_RELAXED, __HIP_MEMORY_SCOPE_AGENT);
}
__device__ inline void  pst_i(int* p, size_t i, int v) {
    __hip_atomic_store(p + i, v, __ATOMIC_RELAXED, __HIP_MEMORY_SCOPE_AGENT);
}
__device__ inline float pld_f(const float* p, size_t i) {
    return __hip_atomic_load(p + i, __ATOMIC_RELAXED, __HIP_MEMORY_SCOPE_AGENT);
}
__device__ inline int   pld_i(const int* p, size_t i) {
    return __hip_atomic_load(p + i, __ATOMIC_RELAXED, __HIP_MEMORY_SCOPE_AGENT);
}

// ---- stage chunk tiles [t0, t0+nt) into LDS (32-row tiles, 40 B row pitch) ----
// row g >= NG -> all-NaN halfs (MFMA output NaN; scrub/mask kills them)
__device__ inline void stage_sh(const float* __restrict__ gv, half4* lds4, int t0, int nt) {
    const int nrows = nt * 32;
    for (int lr = threadIdx.x; lr < nrows; lr += 256) {
        int g = t0 * 32 + lr;
        half4 s0, s1, s2, s3;
        if (g >= NG) {
            const _Float16 qn = (_Float16)__builtin_nanf("");
            s0 = (half4){qn, qn, qn, qn}; s1 = s0; s2 = s0; s3 = s0;
        } else {
            float x = gv[3 * g + 0], y = gv[3 * g + 1], z = gv[3 * g + 2];
            float n2 = x * x + y * y + z * z;
            float rn = __frsqrt_rn(fmaxf(n2, 1e-24f));
            float vx = x * rn, vy = y * rn, vz = z * rn;
            float x2 = vx * vx, y2 = vy * vy, z2 = vz * vz;
            const float c_m4 = (float)(0.75 * sqrt(35.0 / M_PI));
            const float c_m3 = (float)(0.75 * sqrt(35.0 / (2.0 * M_PI)));
            const float c_m2 = (float)(0.75 * sqrt(5.0 / M_PI));
            const float c_m1 = (float)(0.75 * sqrt(5.0 / (2.0 * M_PI)));
            const float c_0  = (float)((3.0 / 16.0) * sqrt(1.0 / M_PI));
            const float c_p2 = (float)((3.0 / 8.0) * sqrt(5.0 / M_PI));
            const float c_p4 = (float)((3.0 / 16.0) * sqrt(35.0 / M_PI));
            s0[0] = (_Float16)(c_m4 * vx * vy * (x2 - y2));
            s0[1] = (_Float16)(c_m3 * vy * vz * (3.0f * x2 - y2));
            s0[2] = (_Float16)(c_m2 * vx * vy * (7.0f * z2 - 1.0f));
            s0[3] = (_Float16)(c_m1 * vy * vz * (7.0f * z2 - 3.0f));
            s1[0] = (_Float16)(c_0  * (35.0f * z2 * z2 - 30.0f * z2 + 3.0f));
            s1[1] = (_Float16)(c_m1 * vx * vz * (7.0f * z2 - 3.0f));
            s1[2] = (_Float16)(c_p2 * (x2 - y2) * (7.0f * z2 - 1.0f));
            s1[3] = (_Float16)(c_m3 * vx * vz * (x2 - y2));
            s2[0] = (_Float16)(c_p4 * (x2 * x2 - 6.0f * x2 * y2 + y2 * y2));  // k=8
            s2[1] = (_Float16)x;   // k=9..11: raw grid vec (pass2 dot)
            s2[2] = (_Float16)y;
            s2[3] = (_Float16)z;
            s3 = (half4){0, 0, 0, 0};      // k=12..15 = 0
        }
        half4* row = lds4 + lr * 5;        // 5 half4 = 20 halfs = 40 B pitch (bank-friendly)
        row[0] = s0; row[1] = s1; row[2] = s2; row[3] = s3;
    }
}

// B-operand frag (f4 for one b column): B[k][col]: col=lane&31, k=(lane>>5)*8+j.
__device__ inline half8 make_bfrag(const float* __restrict__ f4, int b, int kh) {
    half8 a = {0, 0, 0, 0, 0, 0, 0, 0};
    const float* fr = f4 + (size_t)b * 9;
    if (kh == 0) {
#pragma unroll
        for (int j = 0; j < 8; ++j) a[j] = (_Float16)fr[j];
    } else {
        a[0] = (_Float16)fr[8];      // k=8
    }
    return a;
}

// merge (v2,g2) into (v,g) with numpy first-max semantics
__device__ inline void merge_vg(float& v, int& g, float v2, int g2) {
    bool take = (v2 > v) || (v2 == v && g2 < g);
    v = take ? v2 : v;
    g = take ? g2 : g;
}

// last-block detection (r9-proven): (old % NCH == NCH-1) selects exactly one block per
// x for ANY counter start value (20 consecutive u64s hit each residue once) -> no init.
// RELAXED fetch_add: __syncthreads() drains vmcnt(0) so this block's pst stores are
// ack'd at the LLC before the bump; program order does the rest. No L2 flush.
__device__ inline bool last_block_flag(unsigned long long* ctr, int* flag) {
    __syncthreads();
    if (threadIdx.x == 0) {
        unsigned long long old = __hip_atomic_fetch_add(ctr + blockIdx.x, 1ull,
                                                        __ATOMIC_RELAXED,
                                                        __HIP_MEMORY_SCOPE_AGENT);
        *flag = ((unsigned)(old % NCH) == NCH - 1);
    }
    __syncthreads();
    return *flag != 0;
}

// ---------------- Kernel 1: pass-1 argmax, raw tree + end re-derivation ----------------
__global__ __launch_bounds__(256, 6) void k_pass1(const float* __restrict__ f4,
                                                  const float* __restrict__ gv,
                                                  float* __restrict__ P1v,
                                                  int* __restrict__ P1i,
                                                  float* __restrict__ zax,
                                                  unsigned long long* ctr1) {
    __shared__ half4 lds4[MAXTPC * 32 * 5];    // 20480 B -> 8 blocks/CU
    const int lane = threadIdx.x & 63;
    const int w = threadIdx.x >> 6;
    const int W = blockIdx.x * 4 + w;          // b-tile; b = 32W .. 32W+31
    const int n = lane & 31, kh = lane >> 5;
    const int chunk = blockIdx.y;
    const int b = W * 32 + n;

    const int t0 = (NGT * chunk) / NCH;
    const int t1 = (NGT * (chunk + 1)) / NCH;
    const int nt = t1 - t0;
    const bool tailchunk = (chunk == NCH - 1);

    stage_sh(gv, lds4, t0, nt);
    const half8 bf = make_bfrag(f4, b, kh);
    __syncthreads();

    const floatx16 zero16 = {0.f,0.f,0.f,0.f, 0.f,0.f,0.f,0.f, 0.f,0.f,0.f,0.f, 0.f,0.f,0.f,0.f};
    float run = -INFINITY; int bt = 0;

    const half4* lp = lds4 + n * 5 + kh * 2;   // 8 halfs at k-offset kh*8
    half4 a0 = lp[0], a1 = lp[1]; lp += 32 * 5;

    for (int t = 0; t < nt; ++t) {
        half4 b0, b1;
        if (t < nt - 1) { b0 = lp[0]; b1 = lp[1]; lp += 32 * 5; }
        half8 af = __builtin_shufflevector(a0, a1, 0, 1, 2, 3, 4, 5, 6, 7);
        floatx16 c = __builtin_amdgcn_mfma_f32_32x32x16_f16(af, bf, zero16, 0, 0, 0);
        if (tailchunk && t == nt - 1) {        // scrub tail NaNs (uniform cond, once)
#pragma unroll
            for (int r = 0; r < 16; ++r) c[r] = fmaxf(c[r], -3.0e38f);
        }
        float tm = tree16(c);                  // 7 max3 + 1 max on RAW values
        bt = (tm > run) ? t : bt;              // first-max across tiles (strict >)
        run = fmaxf(run, tm);
        a0 = b0; a1 = b1;
    }
    // ---- re-derive winning reg: recompute tile bt (MFMA deterministic) ----
    {
        const half4* lq = lds4 + n * 5 + kh * 2 + bt * (32 * 5);
        half4 ra0 = lq[0], ra1 = lq[1];
        half8 raf = __builtin_shufflevector(ra0, ra1, 0, 1, 2, 3, 4, 5, 6, 7);
        floatx16 c = __builtin_amdgcn_mfma_f32_32x32x16_f16(raf, bf, zero16, 0, 0, 0);
        if (tailchunk && bt == nt - 1) {
#pragma unroll
            for (int r = 0; r < 16; ++r) c[r] = fmaxf(c[r], -3.0e38f);
        }
        int rwin = 0;
#pragma unroll
        for (int r = 15; r >= 0; --r) rwin = (c[r] == run) ? r : rwin;  // smallest r
        int g = (t0 + bt) * 32 + ROWMAP(rwin, kh);
        float v = run;
        merge_vg(v, g, __shfl_xor(v, 32), __shfl_xor(g, 32));
        if (kh == 0) {
            pst_f(P1v, (size_t)chunk * NB + b, v);
            pst_i(P1i, (size_t)chunk * NB + b, g);
        }
    }

    // ---- folded z-reduce: exactly one block per x does it, once all 20 chunks stored ----
    if (last_block_flag(ctr1, (int*)lds4) && threadIdx.x < 128) {
        const int b2 = blockIdx.x * 128 + threadIdx.x;
        float bz = -INFINITY; int zi = 0;
#pragma unroll
        for (int cc = 0; cc < NCH; ++cc) {
            float vv = pld_f(P1v, (size_t)cc * NB + b2);
            int   ii = pld_i(P1i, (size_t)cc * NB + b2);
            merge_vg(bz, zi, vv, ii);
        }
        float4 z4 = {gv[3 * zi + 0], gv[3 * zi + 1], gv[3 * zi + 2], 0.f};
        *(float4*)(zax + 4 * (size_t)b2) = z4;   // plain store: consumed next dispatch
    }
}

// ---------------- Kernel 2: pass-2 masked argmax + folded finalize ----------------
__global__ __launch_bounds__(256, 6) void k_pass2(const float* __restrict__ f0,
                                                  const float* __restrict__ f4,
                                                  const float* __restrict__ gv,
                                                  const float* __restrict__ zax,
                                                  float* __restrict__ P2v,
                                                  int* __restrict__ P2i,
                                                  unsigned long long* ctr2,
                                                  float* __restrict__ out) {
    __shared__ half4 lds4[MAXTPC * 32 * 5];
    const int lane = threadIdx.x & 63;
    const int w = threadIdx.x >> 6;
    const int W = blockIdx.x * 4 + w;
    const int n = lane & 31, kh = lane >> 5;
    const int chunk = blockIdx.y;
    const int b = W * 32 + n;

    const int t0 = (NGT * chunk) / NCH;
    const int t1 = (NGT * (chunk + 1)) / NCH;
    const int nt = t1 - t0;

    stage_sh(gv, lds4, t0, nt);
    const half8 bf = make_bfrag(f4, b, kh);
    half8 df = {0, 0, 0, 0, 0, 0, 0, 0};
    if (kh == 1) {                           // z_b at k=9,10,11 -> j=1..3
        const float* zp = zax + 4 * (size_t)b;
        df[1] = (_Float16)zp[0];
        df[2] = (_Float16)zp[1];
        df[3] = (_Float16)zp[2];
    }
    __syncthreads();

    const floatx16 zero16 = {0.f,0.f,0.f,0.f, 0.f,0.f,0.f,0.f, 0.f,0.f,0.f,0.f, 0.f,0.f,0.f,0.f};
    const float ninf = -INFINITY;
    const float lim = 0.2f;
    float run = -INFINITY; int bt = 0;

    const half4* lp = lds4 + n * 5 + kh * 2;
    half4 a0 = lp[0], a1 = lp[1]; lp += 32 * 5;

    for (int t = 0; t < nt; ++t) {
        half4 b0, b1;
        if (t < nt - 1) { b0 = lp[0]; b1 = lp[1]; lp += 32 * 5; }
        half8 af = __builtin_shufflevector(a0, a1, 0, 1, 2, 3, 4, 5, 6, 7);
        floatx16 cs = __builtin_amdgcn_mfma_f32_32x32x16_f16(af, bf, zero16, 0, 0, 0);
        floatx16 cd = __builtin_amdgcn_mfma_f32_32x32x16_f16(af, df, zero16, 0, 0, 0);
        // masked value per reg: sm = (0.2 > |cd|) ? cs : -inf (NaN dot -> -inf, kills tail)
        floatx16 sm;
#pragma unroll
        for (int r = 0; r < 16; ++r) {
            float smv;
            unsigned long long cc;              // private SGPR cond -> 16 independent chains
            asm("v_cmp_gt_f32 %1, %4, |%2|\n\t"
                "v_cndmask_b32 %0, %5, %3, %1"
                : "=v"(smv), "=&s"(cc)
                : "v"(cd[r]), "v"(cs[r]), "s"(lim), "v"(ninf));
            sm[r] = smv;
        }
        float tm = tree16(sm);
        bt = (tm > run) ? t : bt;
        run = fmaxf(run, tm);
        a0 = b0; a1 = b1;
    }
    // ---- re-derive winning reg for tile bt (identical recompute incl. mask) ----
    {
        const half4* lq = lds4 + n * 5 + kh * 2 + bt * (32 * 5);
        half4 ra0 = lq[0], ra1 = lq[1];
        half8 raf = __builtin_shufflevector(ra0, ra1, 0, 1, 2, 3, 4, 5, 6, 7);
        floatx16 cs = __builtin_amdgcn_mfma_f32_32x32x16_f16(raf, bf, zero16, 0, 0, 0);
        floatx16 cd = __builtin_amdgcn_mfma_f32_32x32x16_f16(raf, df, zero16, 0, 0, 0);
        int rwin = 0;
#pragma unroll
        for (int r = 15; r >= 0; --r) {
            float smv = (fabsf(cd[r]) < lim) ? cs[r] : ninf;
            rwin = (smv == run) ? r : rwin;      // smallest matching r
        }
        int g = (t0 + bt) * 32 + ROWMAP(rwin, kh);
        float v = run;
        merge_vg(v, g, __shfl_xor(v, 32), __shfl_xor(g, 32));
        if (kh == 0) {
            pst_f(P2v, (size_t)chunk * NB + b, v);
            pst_i(P2i, (size_t)chunk * NB + b, g);
        }
    }

    // ---- folded finalize: one block per x merges P2 and writes quaternion + boundary ----
    if (last_block_flag(ctr2, (int*)lds4) && threadIdx.x < 128) {
        const int b2 = blockIdx.x * 128 + threadIdx.x;
        float bx = -INFINITY; int xi = 0;
#pragma unroll
        for (int cc = 0; cc < NCH; ++cc) {
            float vv = pld_f(P2v, (size_t)cc * NB + b2);
            int   ii = pld_i(P2i, (size_t)cc * NB + b2);
            merge_vg(bx, xi, vv, ii);
        }
        const float* zp = zax + 4 * (size_t)b2;
        float zr0 = zp[0], zr1 = zp[1], zr2 = zp[2];
        float xr0 = gv[3 * xi], xr1 = gv[3 * xi + 1], xr2 = gv[3 * xi + 2];
        float zn = sqrtf(zr0 * zr0 + zr1 * zr1 + zr2 * zr2);
        float zd = fmaxf(zn, 1e-12f);
        float z0 = zr0 / zd, z1 = zr1 / zd, z2 = zr2 / zd;
        float pr = xr0 * z0 + xr1 * z1 + xr2 * z2;
        float ux = xr0 - pr * z0, uy = xr1 - pr * z1, uz = xr2 - pr * z2;
        float xn = sqrtf(ux * ux + uy * uy + uz * uz);
        float xd = fmaxf(xn, 1e-12f);
        float x0 = ux / xd, x1 = uy / xd, x2 = uz / xd;
        float y0 = z1 * x2 - z2 * x1;
        float y1 = z2 * x0 - z0 * x2;
        float y2 = z0 * x1 - z1 * x0;
        float m00 = x0, m01 = y0, m02 = z0;
        float m10 = x1, m11 = y1, m12 = z1;
        float m20 = x2, m21 = y2, m22 = z2;
        float q0 = sqrtf(fmaxf(1.0f + m00 + m11 + m22, 0.0f));
        float q1 = sqrtf(fmaxf(1.0f + m00 - m11 - m22, 0.0f));
        float q2 = sqrtf(fmaxf(1.0f - m00 + m11 - m22, 0.0f));
        float q3 = sqrtf(fmaxf(1.0f - m00 - m11 + m22, 0.0f));
        int bq = 0; float qb = q0;
        if (q1 > qb) { qb = q1; bq = 1; }
        if (q2 > qb) { qb = q2; bq = 2; }
        if (q3 > qb) { qb = q3; bq = 3; }
        float dd = 2.0f * fmaxf(qb, 0.1f);
        float wq, qx, qy, qz;
        if (bq == 0)      { wq = q0 * q0;  qx = m21 - m12; qy = m02 - m20; qz = m10 - m01; }
        else if (bq == 1) { wq = m21 - m12; qx = q1 * q1;  qy = m10 + m01; qz = m02 + m20; }
        else if (bq == 2) { wq = m02 - m20; qx = m10 + m01; qy = q2 * q2;  qz = m12 + m21; }
        else              { wq = m10 - m01; qx = m20 + m02; qy = m21 + m12; qz = q3 * q3; }
        out[b2 * 4 + 0] = wq / dd;
        out[b2 * 4 + 1] = qx / dd;
        out[b2 * 4 + 2] = qy / dd;
        out[b2 * 4 + 3] = qz / dd;
        out[4 * NB + b2] = f0[b2] * (float)(180.0 / M_PI);
    }
}

extern "C" void kernel_launch(void* const* d_in, const int* in_sizes, int n_in,
                              void* d_out, int out_size, void* d_ws, size_t ws_size,
                              hipStream_t stream) {
    const float* f0 = (const float*)d_in[0];   // [16384, 1]
    const float* f4 = (const float*)d_in[2];   // [16384, 9]
    const float* gv = (const float*)d_in[4];   // [10000, 3]
    float* out = (float*)d_out;
    (void)in_sizes; (void)n_in; (void)out_size; (void)ws_size;

    // ws layout (1.5 MB stride): P1v | P1i | P2v | P2i | zax | ctr1(1KB) | ctr2(1KB)
    char* W = (char*)d_ws;
    float* P1v = (float*)(W + 0);
    int*   P1i = (int*)(W + 0x180000);
    float* P2v = (float*)(W + 2 * 0x180000);
    int*   P2i = (int*)(W + 3 * 0x180000);
    float* zax = (float*)(W + 4 * 0x180000);                    // [NB][4] floats
    unsigned long long* ctr1 = (unsigned long long*)(W + 5 * 0x180000);
    unsigned long long* ctr2 = (unsigned long long*)(W + 5 * 0x180000 + 4096);
    // counters NOT initialized: (old % NCH == NCH-1) works from any start value.

    // 512 b-tiles / 4 waves = 128 blocks x; 20 chunks y = 2560 blocks, 8/CU resident
    dim3 grid2(128, NCH);
    k_pass1<<<grid2, 256, 0, stream>>>(f4, gv, P1v, P1i, zax, ctr1);
    k_pass2<<<grid2, 256, 0, stream>>>(f0, f4, gv, zax, P2v, P2i, ctr2, out);
}

// Round 11
// 95.526 us; speedup vs baseline: 1.6973x; 1.0171x over previous
//
#include <hip/hip_runtime.h>
#include <math.h>
#include <stdint.h>

#define NB 16384
#define NG 10000
#define NGT 320           // padded to 20*16: every chunk = EXACTLY 16 tiles (compile-time loop)
#define NCH 20            // g-chunks; chunk c covers tiles [16c, 16c+16)
#define TPC 16            // tiles/chunk, compile-time; 16*32 rows*40B = 20480 B LDS -> 8 blocks/CU

typedef _Float16 half4 __attribute__((ext_vector_type(4)));
typedef _Float16 half8 __attribute__((ext_vector_type(8)));
typedef float    floatx16 __attribute__((ext_vector_type(16)));

// C/D row map for 32x32x16: row = (r&3) + 8*(r>>2) + 4*kh   (monotone in r for fixed kh)
#define ROWMAP(r, kh) (((r) & 3) + 8 * ((r) >> 2) + 4 * (kh))

__device__ inline float max3f(float a, float b, float c) {
    float d;
    asm("v_max3_f32 %0, %1, %2, %3" : "=v"(d) : "v"(a), "v"(b), "v"(c));
    return d;
}

// 16 -> 1 max tree on raw values: 7 x v_max3 + 1 x v_max.
// v_max/v_max3 are IEEE maxNum: NaN operands LOSE -> padded/NaN rows never win.
__device__ inline float tree16(const floatx16& c) {
    float u0 = max3f(c[0],  c[1],  c[2]);
    float u1 = max3f(c[3],  c[4],  c[5]);
    float u2 = max3f(c[6],  c[7],  c[8]);
    float u3 = max3f(c[9],  c[10], c[11]);
    float u4 = max3f(c[12], c[13], c[14]);
    float u5 = max3f(u0, u1, c[15]);
    float u6 = max3f(u2, u3, u4);
    return fmaxf(u5, u6);
}

// ---- cross-block data through the coherent point (LLC), r2/r9-proven helpers ----
// RELAXED ONLY: agent-scope acquire/release writebacks+invalidates the whole per-XCD
// L2 per op (r8 regression: pass2 58us, FETCH 2.5x, VALUBusy 80->34).
__device__ inline void  pst_f(float* p, size_t i, float v) {
    __hip_atomic_store(p + i, v, __ATOMIC_RELAXED, __HIP_MEMORY_SCOPE_AGENT);
}
__device__ inline void  pst_i(int* p, size_t i, int v) {
    __hip_atomic_store(p + i, v, __ATOMIC_RELAXED, __HIP_MEMORY_SCOPE_AGENT);
}
__device__ inline float pld_f(const float* p, size_t i) {
    return __hip_atomic_load(p + i, __ATOMIC_RELAXED, __HIP_MEMORY_SCOPE_AGENT);
}
__device__ inline int   pld_i(const int* p, size_t i) {
    return __hip_atomic_load(p + i, __ATOMIC_RELAXED, __HIP_MEMORY_SCOPE_AGENT);
}

// ---- stage chunk tiles [16*chunk, 16*chunk+16) into LDS (32-row tiles, 40 B pitch) ----
// rows g >= NG -> all-NaN halfs: NaN loses every v_max/compare downstream (no scrub needed)
__device__ inline void stage_sh(const float* __restrict__ gv, half4* lds4, int t0) {
    for (int lr = threadIdx.x; lr < TPC * 32; lr += 256) {
        int g = t0 * 32 + lr;
        half4 s0, s1, s2, s3;
        if (g >= NG) {
            const _Float16 qn = (_Float16)__builtin_nanf("");
            s0 = (half4){qn, qn, qn, qn}; s1 = s0; s2 = s0; s3 = s0;
        } else {
            float x = gv[3 * g + 0], y = gv[3 * g + 1], z = gv[3 * g + 2];
            float n2 = x * x + y * y + z * z;
            float rn = __frsqrt_rn(fmaxf(n2, 1e-24f));
            float vx = x * rn, vy = y * rn, vz = z * rn;
            float x2 = vx * vx, y2 = vy * vy, z2 = vz * vz;
            const float c_m4 = (float)(0.75 * sqrt(35.0 / M_PI));
            const float c_m3 = (float)(0.75 * sqrt(35.0 / (2.0 * M_PI)));
            const float c_m2 = (float)(0.75 * sqrt(5.0 / M_PI));
            const float c_m1 = (float)(0.75 * sqrt(5.0 / (2.0 * M_PI)));
            const float c_0  = (float)((3.0 / 16.0) * sqrt(1.0 / M_PI));
            const float c_p2 = (float)((3.0 / 8.0) * sqrt(5.0 / M_PI));
            const float c_p4 = (float)((3.0 / 16.0) * sqrt(35.0 / M_PI));
            s0[0] = (_Float16)(c_m4 * vx * vy * (x2 - y2));
            s0[1] = (_Float16)(c_m3 * vy * vz * (3.0f * x2 - y2));
            s0[2] = (_Float16)(c_m2 * vx * vy * (7.0f * z2 - 1.0f));
            s0[3] = (_Float16)(c_m1 * vy * vz * (7.0f * z2 - 3.0f));
            s1[0] = (_Float16)(c_0  * (35.0f * z2 * z2 - 30.0f * z2 + 3.0f));
            s1[1] = (_Float16)(c_m1 * vx * vz * (7.0f * z2 - 3.0f));
            s1[2] = (_Float16)(c_p2 * (x2 - y2) * (7.0f * z2 - 1.0f));
            s1[3] = (_Float16)(c_m3 * vx * vz * (x2 - y2));
            s2[0] = (_Float16)(c_p4 * (x2 * x2 - 6.0f * x2 * y2 + y2 * y2));  // k=8
            s2[1] = (_Float16)x;   // k=9..11: raw grid vec (pass2 dot)
            s2[2] = (_Float16)y;
            s2[3] = (_Float16)z;
            s3 = (half4){0, 0, 0, 0};      // k=12..15 = 0
        }
        half4* row = lds4 + lr * 5;        // 5 half4 = 20 halfs = 40 B pitch (bank-friendly)
        row[0] = s0; row[1] = s1; row[2] = s2; row[3] = s3;
    }
}

// B-operand frag (f4 for one b column): B[k][col]: col=lane&31, k=(lane>>5)*8+j.
__device__ inline half8 make_bfrag(const float* __restrict__ f4, int b, int kh) {
    half8 a = {0, 0, 0, 0, 0, 0, 0, 0};
    const float* fr = f4 + (size_t)b * 9;
    if (kh == 0) {
#pragma unroll
        for (int j = 0; j < 8; ++j) a[j] = (_Float16)fr[j];
    } else {
        a[0] = (_Float16)fr[8];      // k=8
    }
    return a;
}

// merge (v2,g2) into (v,g) with numpy first-max semantics
__device__ inline void merge_vg(float& v, int& g, float v2, int g2) {
    bool take = (v2 > v) || (v2 == v && g2 < g);
    v = take ? v2 : v;
    g = take ? g2 : g;
}

// last-block detection (r9-proven): (old % NCH == NCH-1) selects exactly one block per
// x for ANY counter start value (20 consecutive u64s hit each residue once) -> no init.
// RELAXED fetch_add: __syncthreads() drains vmcnt(0) so this block's pst stores are
// ack'd at the LLC before the bump; program order does the rest. No L2 flush.
__device__ inline bool last_block_flag(unsigned long long* ctr, int* flag) {
    __syncthreads();
    if (threadIdx.x == 0) {
        unsigned long long old = __hip_atomic_fetch_add(ctr + blockIdx.x, 1ull,
                                                        __ATOMIC_RELAXED,
                                                        __HIP_MEMORY_SCOPE_AGENT);
        *flag = ((unsigned)(old % NCH) == NCH - 1);
    }
    __syncthreads();
    return *flag != 0;
}

// ---------------- Kernel 1: pass-1 argmax, raw tree + end re-derivation ----------------
__global__ __launch_bounds__(256, 6) void k_pass1(const float* __restrict__ f4,
                                                  const float* __restrict__ gv,
                                                  float* __restrict__ P1v,
                                                  int* __restrict__ P1i,
                                                  float* __restrict__ zax,
                                                  unsigned long long* ctr1) {
    __shared__ half4 lds4[TPC * 32 * 5];       // 20480 B -> 8 blocks/CU
    const int lane = threadIdx.x & 63;
    const int w = threadIdx.x >> 6;
    const int W = blockIdx.x * 4 + w;          // b-tile; b = 32W .. 32W+31
    const int n = lane & 31, kh = lane >> 5;
    const int chunk = blockIdx.y;
    const int b = W * 32 + n;
    const int t0 = chunk * TPC;                // compile-time-shaped chunk

    stage_sh(gv, lds4, t0);
    const half8 bf = make_bfrag(f4, b, kh);
    __syncthreads();

    const floatx16 zero16 = {0.f,0.f,0.f,0.f, 0.f,0.f,0.f,0.f, 0.f,0.f,0.f,0.f, 0.f,0.f,0.f,0.f};
    float run = -INFINITY; int bt = 0;

    const half4* lp = lds4 + n * 5 + kh * 2;   // 8 halfs at k-offset kh*8; +160 half4/tile

#pragma unroll 2
    for (int t = 0; t < TPC; ++t) {            // compile-time trip count: immediate offsets
        half4 a0 = lp[t * 160], a1 = lp[t * 160 + 1];
        half8 af = __builtin_shufflevector(a0, a1, 0, 1, 2, 3, 4, 5, 6, 7);
        floatx16 c = __builtin_amdgcn_mfma_f32_32x32x16_f16(af, bf, zero16, 0, 0, 0);
        float tm = tree16(c);                  // NaN rows lose automatically
        bt = (tm > run) ? t : bt;              // first-max across tiles (strict >)
        run = fmaxf(run, tm);
    }
    // ---- re-derive winning reg: recompute tile bt (MFMA deterministic) ----
    {
        const half4* lq = lp + bt * 160;
        half4 ra0 = lq[0], ra1 = lq[1];
        half8 raf = __builtin_shufflevector(ra0, ra1, 0, 1, 2, 3, 4, 5, 6, 7);
        floatx16 c = __builtin_amdgcn_mfma_f32_32x32x16_f16(raf, bf, zero16, 0, 0, 0);
        int rwin = 0;
#pragma unroll
        for (int r = 15; r >= 0; --r) rwin = (c[r] == run) ? r : rwin;  // smallest r
        int g = (t0 + bt) * 32 + ROWMAP(rwin, kh);
        float v = run;
        merge_vg(v, g, __shfl_xor(v, 32), __shfl_xor(g, 32));
        if (kh == 0) {
            pst_f(P1v, (size_t)chunk * NB + b, v);
            pst_i(P1i, (size_t)chunk * NB + b, g);
        }
    }

    // ---- folded z-reduce: exactly one block per x does it, once all 20 chunks stored ----
    if (last_block_flag(ctr1, (int*)lds4) && threadIdx.x < 128) {
        const int b2 = blockIdx.x * 128 + threadIdx.x;
        float bz = -INFINITY; int zi = 0;
#pragma unroll
        for (int cc = 0; cc < NCH; ++cc) {
            float vv = pld_f(P1v, (size_t)cc * NB + b2);
            int   ii = pld_i(P1i, (size_t)cc * NB + b2);
            merge_vg(bz, zi, vv, ii);
        }
        float4 z4 = {gv[3 * zi + 0], gv[3 * zi + 1], gv[3 * zi + 2], 0.f};
        *(float4*)(zax + 4 * (size_t)b2) = z4;   // plain store: consumed next dispatch
    }
}

// ---------------- Kernel 2: pass-2 masked argmax + folded finalize ----------------
__global__ __launch_bounds__(256, 6) void k_pass2(const float* __restrict__ f0,
                                                  const float* __restrict__ f4,
                                                  const float* __restrict__ gv,
                                                  const float* __restrict__ zax,
                                                  float* __restrict__ P2v,
                                                  int* __restrict__ P2i,
                                                  unsigned long long* ctr2,
                                                  float* __restrict__ out) {
    __shared__ half4 lds4[TPC * 32 * 5];
    const int lane = threadIdx.x & 63;
    const int w = threadIdx.x >> 6;
    const int W = blockIdx.x * 4 + w;
    const int n = lane & 31, kh = lane >> 5;
    const int chunk = blockIdx.y;
    const int b = W * 32 + n;
    const int t0 = chunk * TPC;

    stage_sh(gv, lds4, t0);
    const half8 bf = make_bfrag(f4, b, kh);
    half8 df = {0, 0, 0, 0, 0, 0, 0, 0};
    if (kh == 1) {                           // z_b at k=9,10,11 -> j=1..3
        const float* zp = zax + 4 * (size_t)b;
        df[1] = (_Float16)zp[0];
        df[2] = (_Float16)zp[1];
        df[3] = (_Float16)zp[2];
    }
    __syncthreads();

    const floatx16 zero16 = {0.f,0.f,0.f,0.f, 0.f,0.f,0.f,0.f, 0.f,0.f,0.f,0.f, 0.f,0.f,0.f,0.f};
    const float ninf = -INFINITY;
    const float lim = 0.2f;
    float run = -INFINITY; int bt = 0;

    const half4* lp = lds4 + n * 5 + kh * 2;

#pragma unroll 2
    for (int t = 0; t < TPC; ++t) {
        half4 a0 = lp[t * 160], a1 = lp[t * 160 + 1];
        half8 af = __builtin_shufflevector(a0, a1, 0, 1, 2, 3, 4, 5, 6, 7);
        floatx16 cs = __builtin_amdgcn_mfma_f32_32x32x16_f16(af, bf, zero16, 0, 0, 0);
        floatx16 cd = __builtin_amdgcn_mfma_f32_32x32x16_f16(af, df, zero16, 0, 0, 0);
        // masked value per reg: sm = (0.2 > |cd|) ? cs : -inf (NaN dot -> -inf, kills pad)
        floatx16 sm;
#pragma unroll
        for (int r = 0; r < 16; ++r) {
            float smv;
            unsigned long long cc;              // private SGPR cond -> 16 independent chains
            asm("v_cmp_gt_f32 %1, %4, |%2|\n\t"
                "v_cndmask_b32 %0, %5, %3, %1"
                : "=v"(smv), "=&s"(cc)
                : "v"(cd[r]), "v"(cs[r]), "s"(lim), "v"(ninf));
            sm[r] = smv;
        }
        float tm = tree16(sm);
        bt = (tm > run) ? t : bt;
        run = fmaxf(run, tm);
    }
    // ---- re-derive winning reg for tile bt (identical recompute incl. mask) ----
    {
        const half4* lq = lp + bt * 160;
        half4 ra0 = lq[0], ra1 = lq[1];
        half8 raf = __builtin_shufflevector(ra0, ra1, 0, 1, 2, 3, 4, 5, 6, 7);
        floatx16 cs = __builtin_amdgcn_mfma_f32_32x32x16_f16(raf, bf, zero16, 0, 0, 0);
        floatx16 cd = __builtin_amdgcn_mfma_f32_32x32x16_f16(raf, df, zero16, 0, 0, 0);
        int rwin = 0;
#pragma unroll
        for (int r = 15; r >= 0; --r) {
            float smv = (fabsf(cd[r]) < lim) ? cs[r] : ninf;
            rwin = (smv == run) ? r : rwin;      // smallest matching r
        }
        int g = (t0 + bt) * 32 + ROWMAP(rwin, kh);
        float v = run;
        merge_vg(v, g, __shfl_xor(v, 32), __shfl_xor(g, 32));
        if (kh == 0) {
            pst_f(P2v, (size_t)chunk * NB + b, v);
            pst_i(P2i, (size_t)chunk * NB + b, g);
        }
    }

    // ---- folded finalize: one block per x merges P2 and writes quaternion + boundary ----
    if (last_block_flag(ctr2, (int*)lds4) && threadIdx.x < 128) {
        const int b2 = blockIdx.x * 128 + threadIdx.x;
        float bx = -INFINITY; int xi = 0;
#pragma unroll
        for (int cc = 0; cc < NCH; ++cc) {
            float vv = pld_f(P2v, (size_t)cc * NB + b2);
            int   ii = pld_i(P2i, (size_t)cc * NB + b2);
            merge_vg(bx, xi, vv, ii);
        }
        const float* zp = zax + 4 * (size_t)b2;
        float zr0 = zp[0], zr1 = zp[1], zr2 = zp[2];
        float xr0 = gv[3 * xi], xr1 = gv[3 * xi + 1], xr2 = gv[3 * xi + 2];
        float zn = sqrtf(zr0 * zr0 + zr1 * zr1 + zr2 * zr2);
        float zd = fmaxf(zn, 1e-12f);
        float z0 = zr0 / zd, z1 = zr1 / zd, z2 = zr2 / zd;
        float pr = xr0 * z0 + xr1 * z1 + xr2 * z2;
        float ux = xr0 - pr * z0, uy = xr1 - pr * z1, uz = xr2 - pr * z2;
        float xn = sqrtf(ux * ux + uy * uy + uz * uz);
        float xd = fmaxf(xn, 1e-12f);
        float x0 = ux / xd, x1 = uy / xd, x2 = uz / xd;
        float y0 = z1 * x2 - z2 * x1;
        float y1 = z2 * x0 - z0 * x2;
        float y2 = z0 * x1 - z1 * x0;
        float m00 = x0, m01 = y0, m02 = z0;
        float m10 = x1, m11 = y1, m12 = z1;
        float m20 = x2, m21 = y2, m22 = z2;
        float q0 = sqrtf(fmaxf(1.0f + m00 + m11 + m22, 0.0f));
        float q1 = sqrtf(fmaxf(1.0f + m00 - m11 - m22, 0.0f));
        float q2 = sqrtf(fmaxf(1.0f - m00 + m11 - m22, 0.0f));
        float q3 = sqrtf(fmaxf(1.0f - m00 - m11 + m22, 0.0f));
        int bq = 0; float qb = q0;
        if (q1 > qb) { qb = q1; bq = 1; }
        if (q2 > qb) { qb = q2; bq = 2; }
        if (q3 > qb) { qb = q3; bq = 3; }
        float dd = 2.0f * fmaxf(qb, 0.1f);
        float wq, qx, qy, qz;
        if (bq == 0)      { wq = q0 * q0;  qx = m21 - m12; qy = m02 - m20; qz = m10 - m01; }
        else if (bq == 1) { wq = m21 - m12; qx = q1 * q1;  qy = m10 + m01; qz = m02 + m20; }
        else if (bq == 2) { wq = m02 - m20; qx = m10 + m01; qy = q2 * q2;  qz = m12 + m21; }
        else              { wq = m10 - m01; qx = m20 + m02; qy = m21 + m12; qz = q3 * q3; }
        out[b2 * 4 + 0] = wq / dd;
        out[b2 * 4 + 1] = qx / dd;
        out[b2 * 4 + 2] = qy / dd;
        out[b2 * 4 + 3] = qz / dd;
        out[4 * NB + b2] = f0[b2] * (float)(180.0 / M_PI);
    }
}

extern "C" void kernel_launch(void* const* d_in, const int* in_sizes, int n_in,
                              void* d_out, int out_size, void* d_ws, size_t ws_size,
                              hipStream_t stream) {
    const float* f0 = (const float*)d_in[0];   // [16384, 1]
    const float* f4 = (const float*)d_in[2];   // [16384, 9]
    const float* gv = (const float*)d_in[4];   // [10000, 3]
    float* out = (float*)d_out;
    (void)in_sizes; (void)n_in; (void)out_size; (void)ws_size;

    // ws layout (1.5 MB stride): P1v | P1i | P2v | P2i | zax | ctr1(1KB) | ctr2(1KB)
    char* W = (char*)d_ws;
    float* P1v = (float*)(W + 0);
    int*   P1i = (int*)(W + 0x180000);
    float* P2v = (float*)(W + 2 * 0x180000);
    int*   P2i = (int*)(W + 3 * 0x180000);
    float* zax = (float*)(W + 4 * 0x180000);                    // [NB][4] floats
    unsigned long long* ctr1 = (unsigned long long*)(W + 5 * 0x180000);
    unsigned long long* ctr2 = (unsigned long long*)(W + 5 * 0x180000 + 4096);
    // counters NOT initialized: (old % NCH == NCH-1) works from any start value.

    // 512 b-tiles / 4 waves = 128 blocks x; 20 chunks y = 2560 blocks
    dim3 grid2(128, NCH);
    k_pass1<<<grid2, 256, 0, stream>>>(f4, gv, P1v, P1i, zax, ctr1);
    k_pass2<<<grid2, 256, 0, stream>>>(f0, f4, gv, zax, P2v, P2i, ctr2, out);
}